// Round 6
// baseline (5639.774 us; speedup 1.0000x reference)
//
#include <hip/hip_runtime.h>
#include <math.h>

#define B_SZ   4096
#define T_SZ   60
#define F_SZ   30
#define H_ENC  256
#define HD_DEC 100
#define LATD   256
#define DIN_P  76    // 74 padded to multiple of 4
#define DEC_IN 279   // 256 + 9 + 14
#define DEC_IN_P 280

// ---------------- workspace layout (float offsets) ----------------
// Packed weights: [k][unit][gate] float4 (gate-interleaved) for coalesced 16B loads.
enum {
  OFF_PIH_F = 0,                            // 76*256 float4
  OFF_PHH_F = OFF_PIH_F + 76*256*4,         // 256*256 float4
  OFF_PIH_B = OFF_PHH_F + 256*256*4,
  OFF_PHH_B = OFF_PIH_B + 76*256*4,
  OFF_PLAT  = OFF_PHH_B + 256*256*4,        // 256*256 float2 {mu,lv}
  OFF_P1I   = OFF_PLAT  + 256*256*2,        // 280*100 float4
  OFF_P1H   = OFF_P1I   + 280*100*4,        // 100*100 float4
  OFF_P2I   = OFF_P1H   + 100*100*4,
  OFF_P2H   = OFF_P2I   + 100*100*4,
  OFF_WG1T  = OFF_P2H   + 100*100*4,        // [100][25]
  OFF_BE_F  = OFF_WG1T  + 100*25,           // [1024]
  OFF_BE_B  = OFF_BE_F  + 1024,
  OFF_BE1   = OFF_BE_B  + 1024,             // [400]
  OFF_BE2   = OFF_BE1   + 400,
  OFF_HF    = OFF_BE2   + 400,              // [4096][256]
  OFF_HB    = OFF_HF    + B_SZ*H_ENC,
  OFF_Z     = OFF_HB    + B_SZ*H_ENC,       // [4096][256]
  OFF_H1    = OFF_Z     + B_SZ*LATD,        // [4096][100]
  OFF_C1    = OFF_H1    + B_SZ*HD_DEC,
  OFF_H2    = OFF_C1    + B_SZ*HD_DEC,
  OFF_C2    = OFF_H2    + B_SZ*HD_DEC,
  OFF_DLQ   = OFF_C2    + B_SZ*HD_DEC,      // [4096][9]
  OFF_XBUF  = OFF_DLQ   + B_SZ*9,           // [4096][25]
  OFF_MU    = OFF_XBUF  + B_SZ*25,          // [25]
  OFF_RSTD  = OFF_MU    + 25,
  WS_FLOATS = OFF_RSTD  + 25
};

__device__ __forceinline__ float sigf(float x) { return 1.0f / (1.0f + expf(-x)); }

// ---------------- prep: gate-interleaved packs + bias sums ----------------
struct PJob { const float* src; const float* src2; float* dst; int U, C, Kp, G; };
struct PrepArgs { PJob j[14]; };

__global__ __launch_bounds__(256) void prep_kernel(PrepArgs a) {
  int gtid = blockIdx.x * blockDim.x + threadIdx.x;
  int stride = gridDim.x * blockDim.x;
  for (int jj = 0; jj < 14; ++jj) {
    PJob jb = a.j[jj];
    if (jb.src2) {
      for (int i = gtid; i < jb.U; i += stride) jb.dst[i] = jb.src[i] + jb.src2[i];
    } else {
      int total = jb.Kp * jb.U;
      for (int i = gtid; i < total; i += stride) {
        int k = i / jb.U, u = i - k * jb.U;
        float* d = jb.dst + (size_t)i * jb.G;
        for (int g = 0; g < jb.G; ++g)
          d[g] = (k < jb.C) ? jb.src[(g * jb.U + u) * jb.C + k] : 0.0f;
      }
    }
  }
}

// 4-wide fma chain: acc_g += dot(w0..w3 component g, xv)
#define GDOT(acc, c, w0, w1, w2, w3, xv) \
  acc = fmaf((w0).c, (xv).x, fmaf((w1).c, (xv).y, fmaf((w2).c, (xv).z, fmaf((w3).c, (xv).w, acc))))

// ---------------- encoder: both directions, persistent over T ----------------
// 512 blocks: [0,256) forward over batch slices of 16, [256,512) backward.
// 256 threads: ug=tid&127 owns units ug and ug+128; (tid>>7) picks row-half
// (8 of the block's 16 rows). Each ds_read_b128 of x/h now feeds 32 FMAs
// (2 units x 4 gates x 4 k) -- halves LDS-pipe instructions vs 1-unit/thread,
// which round-5 counters showed to be the limiter (VALUBusy 69% ~= FMA/LDS).
__global__ __launch_bounds__(256) void enc_kernel(
    const float* __restrict__ seq, const int* __restrict__ seq_len,
    const int* __restrict__ ymd, const int* __restrict__ acq,
    const float* __restrict__ Ea0, const float* __restrict__ Ea1, const float* __restrict__ Ea2,
    const float* __restrict__ Es0, const float* __restrict__ Es1, const float* __restrict__ Es2,
    const float4* __restrict__ PihF, const float4* __restrict__ PhhF, const float* __restrict__ be_f,
    const float4* __restrict__ PihB, const float4* __restrict__ PhhB, const float* __restrict__ be_b,
    float* __restrict__ hf_out, float* __restrict__ hb_out)
{
  const int tid = threadIdx.x;
  const bool bwd = blockIdx.x >= 256;
  const int b0 = (blockIdx.x & 255) * 16;
  const float4* __restrict__ Pih = bwd ? PihB : PihF;
  const float4* __restrict__ Phh = bwd ? PhhB : PhhF;
  const float* __restrict__ be   = bwd ? be_b : be_f;
  float* __restrict__ hout = bwd ? hb_out : hf_out;

  __shared__ float x_s[16][80];        // DIN padded; cols 74..79 stay 0
  __shared__ float h_s[16][H_ENC];
  __shared__ int   len_s[16];
  __shared__ int   maxlen_s;

  for (int i = tid; i < 16 * 80; i += 256) (&x_s[0][0])[i] = 0.0f;
  for (int i = tid; i < 16 * H_ENC; i += 256) (&h_s[0][0])[i] = 0.0f;
  if (tid < 16) len_s[tid] = seq_len[b0 + tid];
  __syncthreads();

  if (tid == 0) {
    int m = 0;
    for (int r = 0; r < 16; ++r) m = max(m, len_s[r]);
    maxlen_s = m;
  }

  // acquisition embeddings (constant over t): x[30..57]
  for (int i = tid; i < 16 * 28; i += 256) {
    int r = i / 28, j = i - r * 28;
    const int* aq = &acq[(b0 + r) * 3];
    float v;
    if (j < 16)      v = Ea0[aq[0] * 16 + j];
    else if (j < 24) v = Ea1[aq[1] * 8 + (j - 16)];
    else             v = Ea2[aq[2] * 4 + (j - 24)];
    x_s[r][30 + j] = v;
  }

  const int ug = tid & 127;            // unit pair: ug, ug+128
  const int r0 = (tid >> 7) * 8;       // this thread's 8 rows
  const float biA0 = be[ug],       biA1 = be[256 + ug],
              biA2 = be[512 + ug], biA3 = be[768 + ug];
  const float biB0 = be[128 + ug],       biB1 = be[384 + ug],
              biB2 = be[640 + ug],       biB3 = be[896 + ug];

  float cA[8], cB[8];
  #pragma unroll
  for (int r = 0; r < 8; ++r) { cA[r] = 0.0f; cB[r] = 0.0f; }

  __syncthreads();
  const int maxlen = maxlen_s;

  for (int t = 0; t < maxlen; ++t) {
    // ---- stage x (seq features + date embeddings) ----
    for (int i = tid; i < 16 * F_SZ; i += 256) {
      int r = i / F_SZ, k = i - r * F_SZ;
      int len = len_s[r];
      int te = bwd ? max(len - 1 - t, 0) : t;
      x_s[r][k] = seq[((b0 + r) * T_SZ + te) * F_SZ + k];
    }
    {
      int r = tid >> 4, j = tid & 15;  // 256 == 16 rows * 16 vals
      int len = len_s[r];
      int te = bwd ? max(len - 1 - t, 0) : t;
      const int* ym = &ymd[((b0 + r) * T_SZ + te) * 3];
      float v;
      if (j < 8)       v = Es0[ym[0] * 8 + j];
      else if (j < 12) v = Es1[ym[1] * 4 + (j - 8)];
      else             v = Es2[ym[2] * 4 + (j - 12)];
      x_s[r][58 + j] = v;
    }
    __syncthreads();

    // ---- gates: 2 units x 4 gates x 8 rows per thread ----
    float aA0[8], aA1[8], aA2[8], aA3[8];
    float aB0[8], aB1[8], aB2[8], aB3[8];
    #pragma unroll
    for (int r = 0; r < 8; ++r) {
      aA0[r] = biA0; aA1[r] = biA1; aA2[r] = biA2; aA3[r] = biA3;
      aB0[r] = biB0; aB1[r] = biB1; aB2[r] = biB2; aB3[r] = biB3;
    }

    for (int k = 0; k < DIN_P; k += 4) {
      const float4 wa0 = Pih[(k + 0) * 256 + ug];
      const float4 wa1 = Pih[(k + 1) * 256 + ug];
      const float4 wa2 = Pih[(k + 2) * 256 + ug];
      const float4 wa3 = Pih[(k + 3) * 256 + ug];
      const float4 wb0 = Pih[(k + 0) * 256 + 128 + ug];
      const float4 wb1 = Pih[(k + 1) * 256 + 128 + ug];
      const float4 wb2 = Pih[(k + 2) * 256 + 128 + ug];
      const float4 wb3 = Pih[(k + 3) * 256 + 128 + ug];
      #pragma unroll
      for (int r = 0; r < 8; ++r) {
        const float4 xv = *reinterpret_cast<const float4*>(&x_s[r0 + r][k]);
        GDOT(aA0[r], x, wa0, wa1, wa2, wa3, xv);
        GDOT(aA1[r], y, wa0, wa1, wa2, wa3, xv);
        GDOT(aA2[r], z, wa0, wa1, wa2, wa3, xv);
        GDOT(aA3[r], w, wa0, wa1, wa2, wa3, xv);
        GDOT(aB0[r], x, wb0, wb1, wb2, wb3, xv);
        GDOT(aB1[r], y, wb0, wb1, wb2, wb3, xv);
        GDOT(aB2[r], z, wb0, wb1, wb2, wb3, xv);
        GDOT(aB3[r], w, wb0, wb1, wb2, wb3, xv);
      }
    }
    for (int k = 0; k < H_ENC; k += 4) {
      const float4 wa0 = Phh[(k + 0) * 256 + ug];
      const float4 wa1 = Phh[(k + 1) * 256 + ug];
      const float4 wa2 = Phh[(k + 2) * 256 + ug];
      const float4 wa3 = Phh[(k + 3) * 256 + ug];
      const float4 wb0 = Phh[(k + 0) * 256 + 128 + ug];
      const float4 wb1 = Phh[(k + 1) * 256 + 128 + ug];
      const float4 wb2 = Phh[(k + 2) * 256 + 128 + ug];
      const float4 wb3 = Phh[(k + 3) * 256 + 128 + ug];
      #pragma unroll
      for (int r = 0; r < 8; ++r) {
        const float4 hv = *reinterpret_cast<const float4*>(&h_s[r0 + r][k]);
        GDOT(aA0[r], x, wa0, wa1, wa2, wa3, hv);
        GDOT(aA1[r], y, wa0, wa1, wa2, wa3, hv);
        GDOT(aA2[r], z, wa0, wa1, wa2, wa3, hv);
        GDOT(aA3[r], w, wa0, wa1, wa2, wa3, hv);
        GDOT(aB0[r], x, wb0, wb1, wb2, wb3, hv);
        GDOT(aB1[r], y, wb0, wb1, wb2, wb3, hv);
        GDOT(aB2[r], z, wb0, wb1, wb2, wb3, hv);
        GDOT(aB3[r], w, wb0, wb1, wb2, wb3, hv);
      }
    }

    // ---- cell update (masked) ----
    #pragma unroll
    for (int r = 0; r < 8; ++r) {
      if (t < len_s[r0 + r]) {
        float ig = sigf(aA0[r]), fg = sigf(aA1[r]);
        float gg = tanhf(aA2[r]), og = sigf(aA3[r]);
        float cn = fg * cA[r] + ig * gg;
        cA[r] = cn;
        aA0[r] = og * tanhf(cn);
        ig = sigf(aB0[r]); fg = sigf(aB1[r]);
        gg = tanhf(aB2[r]); og = sigf(aB3[r]);
        cn = fg * cB[r] + ig * gg;
        cB[r] = cn;
        aB0[r] = og * tanhf(cn);
      }
    }
    __syncthreads();                   // all h_s reads of this step done
    #pragma unroll
    for (int r = 0; r < 8; ++r) {
      if (t < len_s[r0 + r]) {
        h_s[r0 + r][ug]       = aA0[r];
        h_s[r0 + r][128 + ug] = aB0[r];
      }
    }
    __syncthreads();                   // new h visible; x_s safe to overwrite
  }

  #pragma unroll
  for (int r = 0; r < 8; ++r) {
    hout[(b0 + r0 + r) * H_ENC + ug]       = h_s[r0 + r][ug];
    hout[(b0 + r0 + r) * H_ENC + 128 + ug] = h_s[r0 + r][128 + ug];
  }
}

// ---------------- latent: lat = (hf+hb)@WlatT + b; z; dlq0; zero decoder state ----------------
__global__ __launch_bounds__(256) void latent_kernel(
    const float* __restrict__ hf, const float* __restrict__ hb,
    const float2* __restrict__ Plat, const float* __restrict__ b_lat,
    const float* __restrict__ z_noise, const float* __restrict__ seq,
    const int* __restrict__ seq_len,
    float* __restrict__ z, float* __restrict__ dlq,
    float* __restrict__ h1w, float* __restrict__ c1w,
    float* __restrict__ h2w, float* __restrict__ c2w)
{
  const int tid = threadIdx.x;
  const int b0 = blockIdx.x * 16;
  __shared__ float hs[16][H_ENC];
  for (int i = tid; i < 16 * H_ENC; i += 256)
    (&hs[0][0])[i] = hf[b0 * H_ENC + i] + hb[b0 * H_ENC + i];
  __syncthreads();

  const int u = tid;
  const float bm = b_lat[u], bv = b_lat[LATD + u];
  float am[16], av[16];
  #pragma unroll
  for (int r = 0; r < 16; ++r) { am[r] = bm; av[r] = bv; }

  for (int k = 0; k < H_ENC; k += 4) {
    const float2 p0 = Plat[(k + 0) * 256 + u];
    const float2 p1 = Plat[(k + 1) * 256 + u];
    const float2 p2 = Plat[(k + 2) * 256 + u];
    const float2 p3 = Plat[(k + 3) * 256 + u];
    #pragma unroll
    for (int r = 0; r < 16; ++r) {
      const float4 hv = *reinterpret_cast<const float4*>(&hs[r][k]);
      am[r] = fmaf(p0.x, hv.x, fmaf(p1.x, hv.y, fmaf(p2.x, hv.z, fmaf(p3.x, hv.w, am[r]))));
      av[r] = fmaf(p0.y, hv.x, fmaf(p1.y, hv.y, fmaf(p2.y, hv.z, fmaf(p3.y, hv.w, av[r]))));
    }
  }
  #pragma unroll
  for (int r = 0; r < 16; ++r) {
    int b = b0 + r;
    z[b * LATD + u] = am[r] + sqrtf(expf(av[r])) * z_noise[b * LATD + u];
  }
  if (u < HD_DEC) {
    #pragma unroll
    for (int r = 0; r < 16; ++r) {
      int b = b0 + r;
      h1w[b * HD_DEC + u] = 0.0f; c1w[b * HD_DEC + u] = 0.0f;
      h2w[b * HD_DEC + u] = 0.0f; c2w[b * HD_DEC + u] = 0.0f;
    }
  }
  if (u < 9) {
    #pragma unroll
    for (int r = 0; r < 16; ++r) {
      int b = b0 + r;
      int len = seq_len[b];
      dlq[b * 9 + u] = seq[(b * T_SZ + (len - 1)) * F_SZ + 21 + u];
    }
  }
}

// ---------------- decoder cell step: LSTM1 + LSTM2 + x=relu(h2@Wg1T+bg1) ----------------
__global__ __launch_bounds__(256) void dec_cell_kernel(
    const float* __restrict__ z, const float* __restrict__ dlq,
    const float* __restrict__ macro,
    float* __restrict__ h1w, float* __restrict__ c1w,
    float* __restrict__ h2w, float* __restrict__ c2w,
    const float4* __restrict__ P1I, const float4* __restrict__ P1H, const float* __restrict__ be1,
    const float4* __restrict__ P2I, const float4* __restrict__ P2H, const float* __restrict__ be2,
    const float* __restrict__ Wg1T, const float* __restrict__ bg1,
    float* __restrict__ xbuf, int t)
{
  const int tid = threadIdx.x;
  const int b0 = blockIdx.x * 16;
  __shared__ float di[16][DEC_IN_P];
  __shared__ float h1s[16][HD_DEC];
  __shared__ float h2s[16][HD_DEC];

  for (int i = tid; i < 16 * DEC_IN_P; i += 256) {
    int r = i / DEC_IN_P, k = i - r * DEC_IN_P;
    int b = b0 + r;
    float v;
    if (k < LATD)            v = z[b * LATD + k];
    else if (k < LATD + 9)   v = dlq[b * 9 + (k - LATD)];
    else if (k < DEC_IN)     v = macro[(b * 12 + t) * 14 + (k - LATD - 9)];
    else                     v = 0.0f;
    di[r][k] = v;
  }
  for (int i = tid; i < 16 * HD_DEC; i += 256) {
    int r = i / HD_DEC, k = i - r * HD_DEC;
    h1s[r][k] = h1w[(b0 + r) * HD_DEC + k];
    h2s[r][k] = h2w[(b0 + r) * HD_DEC + k];
  }

  const int u = tid & 127;
  const int grp = tid >> 7;       // 0/1 -> rows [0..8) / [8..16)
  const int r0 = grp * 8;
  const bool act = u < HD_DEC;

  float c1r[8], c2r[8];
  if (act) {
    #pragma unroll
    for (int r = 0; r < 8; ++r) {
      c1r[r] = c1w[(b0 + r0 + r) * HD_DEC + u];
      c2r[r] = c2w[(b0 + r0 + r) * HD_DEC + u];
    }
  }
  __syncthreads();

  // ---- LSTM1 gates ----
  float a0[8], a1[8], a2[8], a3[8];
  if (act) {
    const float b0g = be1[u], b1g = be1[100 + u], b2g = be1[200 + u], b3g = be1[300 + u];
    #pragma unroll
    for (int r = 0; r < 8; ++r) { a0[r] = b0g; a1[r] = b1g; a2[r] = b2g; a3[r] = b3g; }
    for (int k = 0; k < DEC_IN_P; k += 4) {
      const float4 w0 = P1I[(k + 0) * 100 + u];
      const float4 w1 = P1I[(k + 1) * 100 + u];
      const float4 w2 = P1I[(k + 2) * 100 + u];
      const float4 w3 = P1I[(k + 3) * 100 + u];
      #pragma unroll
      for (int r = 0; r < 8; ++r) {
        const float4 xv = *reinterpret_cast<const float4*>(&di[r0 + r][k]);
        GDOT(a0[r], x, w0, w1, w2, w3, xv);
        GDOT(a1[r], y, w0, w1, w2, w3, xv);
        GDOT(a2[r], z, w0, w1, w2, w3, xv);
        GDOT(a3[r], w, w0, w1, w2, w3, xv);
      }
    }
    for (int k = 0; k < HD_DEC; k += 4) {
      const float4 w0 = P1H[(k + 0) * 100 + u];
      const float4 w1 = P1H[(k + 1) * 100 + u];
      const float4 w2 = P1H[(k + 2) * 100 + u];
      const float4 w3 = P1H[(k + 3) * 100 + u];
      #pragma unroll
      for (int r = 0; r < 8; ++r) {
        const float4 hv = *reinterpret_cast<const float4*>(&h1s[r0 + r][k]);
        GDOT(a0[r], x, w0, w1, w2, w3, hv);
        GDOT(a1[r], y, w0, w1, w2, w3, hv);
        GDOT(a2[r], z, w0, w1, w2, w3, hv);
        GDOT(a3[r], w, w0, w1, w2, w3, hv);
      }
    }
  }
  __syncthreads();                 // h1s reads complete
  if (act) {
    #pragma unroll
    for (int r = 0; r < 8; ++r) {
      float ig = sigf(a0[r]), fg = sigf(a1[r]), gg = tanhf(a2[r]), og = sigf(a3[r]);
      float cn = fg * c1r[r] + ig * gg;
      float hn = og * tanhf(cn);
      int b = b0 + r0 + r;
      h1s[r0 + r][u] = hn;
      h1w[b * HD_DEC + u] = hn;
      c1w[b * HD_DEC + u] = cn;
    }
  }
  __syncthreads();                 // new h1 visible

  // ---- LSTM2 gates (x = new h1, h = old h2) ----
  if (act) {
    const float b0g = be2[u], b1g = be2[100 + u], b2g = be2[200 + u], b3g = be2[300 + u];
    #pragma unroll
    for (int r = 0; r < 8; ++r) { a0[r] = b0g; a1[r] = b1g; a2[r] = b2g; a3[r] = b3g; }
    for (int k = 0; k < HD_DEC; k += 4) {
      const float4 w0 = P2I[(k + 0) * 100 + u];
      const float4 w1 = P2I[(k + 1) * 100 + u];
      const float4 w2 = P2I[(k + 2) * 100 + u];
      const float4 w3 = P2I[(k + 3) * 100 + u];
      #pragma unroll
      for (int r = 0; r < 8; ++r) {
        const float4 hv = *reinterpret_cast<const float4*>(&h1s[r0 + r][k]);
        GDOT(a0[r], x, w0, w1, w2, w3, hv);
        GDOT(a1[r], y, w0, w1, w2, w3, hv);
        GDOT(a2[r], z, w0, w1, w2, w3, hv);
        GDOT(a3[r], w, w0, w1, w2, w3, hv);
      }
    }
    for (int k = 0; k < HD_DEC; k += 4) {
      const float4 w0 = P2H[(k + 0) * 100 + u];
      const float4 w1 = P2H[(k + 1) * 100 + u];
      const float4 w2 = P2H[(k + 2) * 100 + u];
      const float4 w3 = P2H[(k + 3) * 100 + u];
      #pragma unroll
      for (int r = 0; r < 8; ++r) {
        const float4 hv = *reinterpret_cast<const float4*>(&h2s[r0 + r][k]);
        GDOT(a0[r], x, w0, w1, w2, w3, hv);
        GDOT(a1[r], y, w0, w1, w2, w3, hv);
        GDOT(a2[r], z, w0, w1, w2, w3, hv);
        GDOT(a3[r], w, w0, w1, w2, w3, hv);
      }
    }
  }
  __syncthreads();                 // h2s reads complete
  if (act) {
    #pragma unroll
    for (int r = 0; r < 8; ++r) {
      float ig = sigf(a0[r]), fg = sigf(a1[r]), gg = tanhf(a2[r]), og = sigf(a3[r]);
      float cn = fg * c2r[r] + ig * gg;
      float hn = og * tanhf(cn);
      int b = b0 + r0 + r;
      h2s[r0 + r][u] = hn;
      h2w[b * HD_DEC + u] = hn;
      c2w[b * HD_DEC + u] = cn;
    }
  }
  __syncthreads();                 // new h2 visible

  // ---- x = relu(h2 @ Wg1T + bg1) ----
  for (int p = tid; p < 16 * 25; p += 256) {
    int r = p / 25, c = p - r * 25;
    float s = bg1[c];
    for (int k = 0; k < HD_DEC; k += 4) {
      const float4 hv = *reinterpret_cast<const float4*>(&h2s[r][k]);
      s += hv.x * Wg1T[k * 25 + c] + hv.y * Wg1T[(k + 1) * 25 + c]
         + hv.z * Wg1T[(k + 2) * 25 + c] + hv.w * Wg1T[(k + 3) * 25 + c];
    }
    xbuf[(b0 + r) * 25 + c] = fmaxf(s, 0.0f);
  }
}

// ---------------- decoder batchnorm stats (deterministic tree reduce) ----------------
__global__ __launch_bounds__(256) void dec_stats_kernel(
    const float* __restrict__ xbuf, float* __restrict__ muv, float* __restrict__ rstdv)
{
  const int col = blockIdx.x;
  const int tid = threadIdx.x;
  __shared__ float red[256];
  float v[16];
  float s = 0.0f;
  #pragma unroll
  for (int i = 0; i < 16; ++i) { v[i] = xbuf[(tid + 256 * i) * 25 + col]; s += v[i]; }
  red[tid] = s; __syncthreads();
  for (int off = 128; off >= 1; off >>= 1) {
    if (tid < off) red[tid] += red[tid + off];
    __syncthreads();
  }
  float mean = red[0] / (float)B_SZ;
  __syncthreads();
  float s2 = 0.0f;
  #pragma unroll
  for (int i = 0; i < 16; ++i) { float d = v[i] - mean; s2 += d * d; }
  red[tid] = s2; __syncthreads();
  for (int off = 128; off >= 1; off >>= 1) {
    if (tid < off) red[tid] += red[tid + off];
    __syncthreads();
  }
  if (tid == 0) {
    muv[col] = mean;
    rstdv[col] = rsqrtf(red[0] / (float)B_SZ + 1e-5f);
  }
}

// ---------------- decoder normalize + dlq = xn@Wg2T + bg2, write output ----------------
__global__ __launch_bounds__(256) void dec_out_kernel(
    const float* __restrict__ xbuf, const float* __restrict__ muv, const float* __restrict__ rstdv,
    const float* __restrict__ gamma, const float* __restrict__ beta,
    const float* __restrict__ Wg2, const float* __restrict__ bg2,
    float* __restrict__ dlq, float* __restrict__ out, int t)
{
  int b = blockIdx.x * 256 + threadIdx.x;
  float xn[25];
  #pragma unroll
  for (int c = 0; c < 25; ++c)
    xn[c] = gamma[c] * (xbuf[b * 25 + c] - muv[c]) * rstdv[c] + beta[c];
  #pragma unroll
  for (int j = 0; j < 9; ++j) {
    float s = bg2[j];
    #pragma unroll
    for (int c = 0; c < 25; ++c) s += xn[c] * Wg2[j * 25 + c];
    dlq[b * 9 + j] = s;
    out[b * 108 + j * 12 + t] = s;
  }
}

// ---------------- host launch ----------------
extern "C" void kernel_launch(void* const* d_in, const int* in_sizes, int n_in,
                              void* d_out, int out_size, void* d_ws, size_t ws_size,
                              hipStream_t stream)
{
  const float* seq     = (const float*)d_in[0];
  const int*   seq_len = (const int*)  d_in[1];
  const int*   ymd     = (const int*)  d_in[2];
  const int*   acq     = (const int*)  d_in[3];
  const float* macro   = (const float*)d_in[4];
  const float* z_noise = (const float*)d_in[5];
  const float* Ea0 = (const float*)d_in[6];
  const float* Ea1 = (const float*)d_in[7];
  const float* Ea2 = (const float*)d_in[8];
  const float* Es0 = (const float*)d_in[9];
  const float* Es1 = (const float*)d_in[10];
  const float* Es2 = (const float*)d_in[11];
  const float* Wih_f = (const float*)d_in[12];
  const float* Whh_f = (const float*)d_in[13];
  const float* bih_f = (const float*)d_in[14];
  const float* bhh_f = (const float*)d_in[15];
  const float* Wih_b = (const float*)d_in[16];
  const float* Whh_b = (const float*)d_in[17];
  const float* bih_b = (const float*)d_in[18];
  const float* bhh_b = (const float*)d_in[19];
  const float* W_lat = (const float*)d_in[20];
  const float* b_lat = (const float*)d_in[21];
  const float* Wih1  = (const float*)d_in[22];
  const float* Whh1  = (const float*)d_in[23];
  const float* bih1  = (const float*)d_in[24];
  const float* bhh1  = (const float*)d_in[25];
  const float* Wih2  = (const float*)d_in[26];
  const float* Whh2  = (const float*)d_in[27];
  const float* bih2  = (const float*)d_in[28];
  const float* bhh2  = (const float*)d_in[29];
  const float* Wg1   = (const float*)d_in[30];
  const float* bg1   = (const float*)d_in[31];
  const float* gamma = (const float*)d_in[32];
  const float* beta  = (const float*)d_in[33];
  const float* Wg2   = (const float*)d_in[34];
  const float* bg2   = (const float*)d_in[35];

  float* ws  = (float*)d_ws;
  float* out = (float*)d_out;

  float* pihF = ws + OFF_PIH_F;
  float* phhF = ws + OFF_PHH_F;
  float* pihB = ws + OFF_PIH_B;
  float* phhB = ws + OFF_PHH_B;
  float* plat = ws + OFF_PLAT;
  float* p1i  = ws + OFF_P1I;
  float* p1h  = ws + OFF_P1H;
  float* p2i  = ws + OFF_P2I;
  float* p2h  = ws + OFF_P2H;
  float* wg1T = ws + OFF_WG1T;
  float* be_f = ws + OFF_BE_F;
  float* be_b = ws + OFF_BE_B;
  float* be1  = ws + OFF_BE1;
  float* be2  = ws + OFF_BE2;
  float* hf   = ws + OFF_HF;
  float* hb   = ws + OFF_HB;
  float* z    = ws + OFF_Z;
  float* h1w  = ws + OFF_H1;
  float* c1w  = ws + OFF_C1;
  float* h2w  = ws + OFF_H2;
  float* c2w  = ws + OFF_C2;
  float* dlq  = ws + OFF_DLQ;
  float* xbuf = ws + OFF_XBUF;
  float* muv  = ws + OFF_MU;
  float* rstdv= ws + OFF_RSTD;

  PrepArgs pa;
  int ji = 0;
  auto PK = [&](const float* s, float* d, int U, int C, int Kp, int G) {
    pa.j[ji].src = s; pa.j[ji].src2 = nullptr; pa.j[ji].dst = d;
    pa.j[ji].U = U; pa.j[ji].C = C; pa.j[ji].Kp = Kp; pa.j[ji].G = G; ++ji;
  };
  auto BS = [&](const float* a, const float* b, float* d, int n) {
    pa.j[ji].src = a; pa.j[ji].src2 = b; pa.j[ji].dst = d;
    pa.j[ji].U = n; pa.j[ji].C = 0; pa.j[ji].Kp = 0; pa.j[ji].G = 0; ++ji;
  };
  PK(Wih_f, pihF, 256, 74, 76, 4);
  PK(Whh_f, phhF, 256, 256, 256, 4);
  PK(Wih_b, pihB, 256, 74, 76, 4);
  PK(Whh_b, phhB, 256, 256, 256, 4);
  PK(W_lat, plat, 256, 256, 256, 2);
  PK(Wih1,  p1i,  100, 279, 280, 4);
  PK(Whh1,  p1h,  100, 100, 100, 4);
  PK(Wih2,  p2i,  100, 100, 100, 4);
  PK(Whh2,  p2h,  100, 100, 100, 4);
  PK(Wg1,   wg1T, 25, 100, 100, 1);
  BS(bih_f, bhh_f, be_f, 1024);
  BS(bih_b, bhh_b, be_b, 1024);
  BS(bih1,  bhh1,  be1,  400);
  BS(bih2,  bhh2,  be2,  400);

  prep_kernel<<<512, 256, 0, stream>>>(pa);

  enc_kernel<<<512, 256, 0, stream>>>(
      seq, seq_len, ymd, acq, Ea0, Ea1, Ea2, Es0, Es1, Es2,
      (const float4*)pihF, (const float4*)phhF, be_f,
      (const float4*)pihB, (const float4*)phhB, be_b, hf, hb);

  latent_kernel<<<256, 256, 0, stream>>>(
      hf, hb, (const float2*)plat, b_lat, z_noise, seq, seq_len,
      z, dlq, h1w, c1w, h2w, c2w);

  for (int t = 0; t < 12; ++t) {
    dec_cell_kernel<<<256, 256, 0, stream>>>(
        z, dlq, macro, h1w, c1w, h2w, c2w,
        (const float4*)p1i, (const float4*)p1h, be1,
        (const float4*)p2i, (const float4*)p2h, be2, wg1T, bg1, xbuf, t);
    dec_stats_kernel<<<25, 256, 0, stream>>>(xbuf, muv, rstdv);
    dec_out_kernel<<<16, 256, 0, stream>>>(
        xbuf, muv, rstdv, gamma, beta, Wg2, bg2, dlq, out, t);
  }
}

// Round 7
// 3960.563 us; speedup vs baseline: 1.4240x; 1.4240x over previous
//
#include <hip/hip_runtime.h>
#include <math.h>

#define B_SZ   4096
#define T_SZ   60
#define F_SZ   30
#define H_ENC  256
#define HD_DEC 100
#define LATD   256
#define DIN_P  76    // 74 padded to multiple of 4
#define DEC_IN 279   // 256 + 9 + 14
#define DEC_IN_P 280

// ---------------- workspace layout (float offsets) ----------------
// Packed weights: [k][unit][gate] float4 (gate-interleaved) for coalesced 16B loads.
enum {
  OFF_PIH_F = 0,                            // 76*256 float4
  OFF_PHH_F = OFF_PIH_F + 76*256*4,         // 256*256 float4
  OFF_PIH_B = OFF_PHH_F + 256*256*4,
  OFF_PHH_B = OFF_PIH_B + 76*256*4,
  OFF_PLAT  = OFF_PHH_B + 256*256*4,        // 256*256 float2 {mu,lv}
  OFF_P1I   = OFF_PLAT  + 256*256*2,        // 280*100 float4
  OFF_P1H   = OFF_P1I   + 280*100*4,        // 100*100 float4
  OFF_P2I   = OFF_P1H   + 100*100*4,
  OFF_P2H   = OFF_P2I   + 100*100*4,
  OFF_WG1T  = OFF_P2H   + 100*100*4,        // [100][25]
  OFF_BE_F  = OFF_WG1T  + 100*25,           // [1024]
  OFF_BE_B  = OFF_BE_F  + 1024,
  OFF_BE1   = OFF_BE_B  + 1024,             // [400]
  OFF_BE2   = OFF_BE1   + 400,
  OFF_HF    = OFF_BE2   + 400,              // [4096][256]
  OFF_HB    = OFF_HF    + B_SZ*H_ENC,
  OFF_Z     = OFF_HB    + B_SZ*H_ENC,       // [4096][256]
  OFF_H1    = OFF_Z     + B_SZ*LATD,        // [4096][100]
  OFF_C1    = OFF_H1    + B_SZ*HD_DEC,
  OFF_H2    = OFF_C1    + B_SZ*HD_DEC,
  OFF_C2    = OFF_H2    + B_SZ*HD_DEC,
  OFF_DLQ   = OFF_C2    + B_SZ*HD_DEC,      // [4096][9]
  OFF_XBUF  = OFF_DLQ   + B_SZ*9,           // [4096][25]
  OFF_MU    = OFF_XBUF  + B_SZ*25,          // [25]
  OFF_RSTD  = OFF_MU    + 25,
  WS_FLOATS = OFF_RSTD  + 25
};

__device__ __forceinline__ float sigf(float x) { return 1.0f / (1.0f + expf(-x)); }

// ---------------- prep: gate-interleaved packs + bias sums ----------------
struct PJob { const float* src; const float* src2; float* dst; int U, C, Kp, G; };
struct PrepArgs { PJob j[14]; };

__global__ __launch_bounds__(256) void prep_kernel(PrepArgs a) {
  int gtid = blockIdx.x * blockDim.x + threadIdx.x;
  int stride = gridDim.x * blockDim.x;
  for (int jj = 0; jj < 14; ++jj) {
    PJob jb = a.j[jj];
    if (jb.src2) {
      for (int i = gtid; i < jb.U; i += stride) jb.dst[i] = jb.src[i] + jb.src2[i];
    } else {
      int total = jb.Kp * jb.U;
      for (int i = gtid; i < total; i += stride) {
        int k = i / jb.U, u = i - k * jb.U;
        float* d = jb.dst + (size_t)i * jb.G;
        for (int g = 0; g < jb.G; ++g)
          d[g] = (k < jb.C) ? jb.src[(g * jb.U + u) * jb.C + k] : 0.0f;
      }
    }
  }
}

// 4-wide fma chain: acc_g += dot(w0..w3 component g, xv)
#define GDOT(acc, c, w0, w1, w2, w3, xv) \
  acc = fmaf((w0).c, (xv).x, fmaf((w1).c, (xv).y, fmaf((w2).c, (xv).z, fmaf((w3).c, (xv).w, acc))))

// ---------------- encoder: balanced strided rows, group early-exit ----------------
// 256 blocks: [0,128) fwd, [128,256) bwd; block c owns rows {c + 128*j : j=0..31}
// (seq_len sorted desc => every block sees the same length spectrum 60..0).
// 1024 threads: u = tid&255 owns unit u for 8 rows; rq = tid>>8 picks row-group
// j in [8rq, 8rq+8) (4 waves, wave-uniform). Group exits gate GEMM when
// t >= len of its longest row (taper); barriers hit by all threads always.
__global__ __launch_bounds__(1024) void enc_kernel(
    const float* __restrict__ seq, const int* __restrict__ seq_len,
    const int* __restrict__ ymd, const int* __restrict__ acq,
    const float* __restrict__ Ea0, const float* __restrict__ Ea1, const float* __restrict__ Ea2,
    const float* __restrict__ Es0, const float* __restrict__ Es1, const float* __restrict__ Es2,
    const float4* __restrict__ PihF, const float4* __restrict__ PhhF, const float* __restrict__ be_f,
    const float4* __restrict__ PihB, const float4* __restrict__ PhhB, const float* __restrict__ be_b,
    float* __restrict__ hf_out, float* __restrict__ hb_out)
{
  const int tid = threadIdx.x;
  const bool bwd = blockIdx.x >= 128;
  const int c = blockIdx.x & 127;
  const float4* __restrict__ Pih = bwd ? PihB : PihF;
  const float4* __restrict__ Phh = bwd ? PhhB : PhhF;
  const float* __restrict__ be   = bwd ? be_b : be_f;
  float* __restrict__ hout = bwd ? hb_out : hf_out;

  __shared__ float x_s[32][80];        // DIN padded; cols 74..79 stay 0
  __shared__ float h_s[32][H_ENC];
  __shared__ int   len_s[32];

  for (int i = tid; i < 32 * 80; i += 1024) (&x_s[0][0])[i] = 0.0f;
  for (int i = tid; i < 32 * H_ENC; i += 1024) (&h_s[0][0])[i] = 0.0f;
  if (tid < 32) len_s[tid] = seq_len[c + 128 * tid];
  __syncthreads();

  // acquisition embeddings (constant over t): x[30..57]
  if (tid < 32 * 28) {
    int r = tid / 28, j = tid - r * 28;
    const int* aq = &acq[(c + 128 * r) * 3];
    float v;
    if (j < 16)      v = Ea0[aq[0] * 16 + j];
    else if (j < 24) v = Ea1[aq[1] * 8 + (j - 16)];
    else             v = Ea2[aq[2] * 4 + (j - 24)];
    x_s[r][30 + j] = v;
  }

  const int u  = tid & 255;
  const int rq = tid >> 8;             // 0..3
  const int j0 = rq * 8;
  const float bi0 = be[u], bi1 = be[256 + u], bi2 = be[512 + u], bi3 = be[768 + u];

  float c_r[8];
  int   lenr[8];
  #pragma unroll
  for (int r = 0; r < 8; ++r) c_r[r] = 0.0f;

  __syncthreads();                     // len_s + embeds visible
  #pragma unroll
  for (int r = 0; r < 8; ++r) lenr[r] = len_s[j0 + r];
  const int maxlen = len_s[0];
  const int mylen  = lenr[0];          // group's longest (rows ranked desc)

  for (int t = 0; t < maxlen; ++t) {
    // ---- stage x (seq features + date embeddings) ----
    {
      int r = tid >> 5, jj = tid & 31; // 1024 = 32 rows * 32 lanes
      if (jj < F_SZ) {
        int len = len_s[r];
        int te = bwd ? max(len - 1 - t, 0) : t;
        x_s[r][jj] = seq[((c + 128 * r) * T_SZ + te) * F_SZ + jj];
      }
    }
    if (tid < 32 * 16) {
      int r = tid >> 4, jj = tid & 15;
      int len = len_s[r];
      int te = bwd ? max(len - 1 - t, 0) : t;
      const int* ym = &ymd[((c + 128 * r) * T_SZ + te) * 3];
      float v;
      if (jj < 8)       v = Es0[ym[0] * 8 + jj];
      else if (jj < 12) v = Es1[ym[1] * 4 + (jj - 8)];
      else              v = Es2[ym[2] * 4 + (jj - 12)];
      x_s[r][58 + jj] = v;
    }
    __syncthreads();                   // A: x(t) ready, h(t-1) visible

    float4 g[8];
    const bool act = (t < mylen);      // wave-uniform group gate
    if (act) {
      #pragma unroll
      for (int r = 0; r < 8; ++r) { g[r].x = bi0; g[r].y = bi1; g[r].z = bi2; g[r].w = bi3; }

      for (int k = 0; k < DIN_P; k += 4) {
        const float4 w0 = Pih[(k + 0) * 256 + u];
        const float4 w1 = Pih[(k + 1) * 256 + u];
        const float4 w2 = Pih[(k + 2) * 256 + u];
        const float4 w3 = Pih[(k + 3) * 256 + u];
        #pragma unroll
        for (int r = 0; r < 8; ++r) {
          const float4 xv = *reinterpret_cast<const float4*>(&x_s[j0 + r][k]);
          GDOT(g[r].x, x, w0, w1, w2, w3, xv);
          GDOT(g[r].y, y, w0, w1, w2, w3, xv);
          GDOT(g[r].z, z, w0, w1, w2, w3, xv);
          GDOT(g[r].w, w, w0, w1, w2, w3, xv);
        }
      }
      for (int k = 0; k < H_ENC; k += 4) {
        const float4 w0 = Phh[(k + 0) * 256 + u];
        const float4 w1 = Phh[(k + 1) * 256 + u];
        const float4 w2 = Phh[(k + 2) * 256 + u];
        const float4 w3 = Phh[(k + 3) * 256 + u];
        #pragma unroll
        for (int r = 0; r < 8; ++r) {
          const float4 hv = *reinterpret_cast<const float4*>(&h_s[j0 + r][k]);
          GDOT(g[r].x, x, w0, w1, w2, w3, hv);
          GDOT(g[r].y, y, w0, w1, w2, w3, hv);
          GDOT(g[r].z, z, w0, w1, w2, w3, hv);
          GDOT(g[r].w, w, w0, w1, w2, w3, hv);
        }
      }

      // ---- cell update (per-row masked); result stashed in g[r].x ----
      #pragma unroll
      for (int r = 0; r < 8; ++r) {
        if (t < lenr[r]) {
          float ig = sigf(g[r].x);
          float fg = sigf(g[r].y);
          float gg = tanhf(g[r].z);
          float og = sigf(g[r].w);
          float cn = fg * c_r[r] + ig * gg;
          c_r[r] = cn;
          g[r].x = og * tanhf(cn);
        }
      }
    }
    __syncthreads();                   // B: all h_s/x_s reads of step t done
    if (act) {
      #pragma unroll
      for (int r = 0; r < 8; ++r) if (t < lenr[r]) h_s[j0 + r][u] = g[r].x;
    }
    // next iteration's barrier A publishes the h writes
  }

  __syncthreads();
  for (int i = tid; i < 32 * H_ENC; i += 1024) {
    int r = i >> 8, uu = i & 255;
    hout[(c + 128 * r) * H_ENC + uu] = h_s[r][uu];
  }
}

// ---------------- latent: lat = (hf+hb)@WlatT + b; z; dlq0; zero decoder state ----------------
__global__ __launch_bounds__(256) void latent_kernel(
    const float* __restrict__ hf, const float* __restrict__ hb,
    const float2* __restrict__ Plat, const float* __restrict__ b_lat,
    const float* __restrict__ z_noise, const float* __restrict__ seq,
    const int* __restrict__ seq_len,
    float* __restrict__ z, float* __restrict__ dlq,
    float* __restrict__ h1w, float* __restrict__ c1w,
    float* __restrict__ h2w, float* __restrict__ c2w)
{
  const int tid = threadIdx.x;
  const int b0 = blockIdx.x * 16;
  __shared__ float hs[16][H_ENC];
  for (int i = tid; i < 16 * H_ENC; i += 256)
    (&hs[0][0])[i] = hf[b0 * H_ENC + i] + hb[b0 * H_ENC + i];
  __syncthreads();

  const int u = tid;
  const float bm = b_lat[u], bv = b_lat[LATD + u];
  float am[16], av[16];
  #pragma unroll
  for (int r = 0; r < 16; ++r) { am[r] = bm; av[r] = bv; }

  for (int k = 0; k < H_ENC; k += 4) {
    const float2 p0 = Plat[(k + 0) * 256 + u];
    const float2 p1 = Plat[(k + 1) * 256 + u];
    const float2 p2 = Plat[(k + 2) * 256 + u];
    const float2 p3 = Plat[(k + 3) * 256 + u];
    #pragma unroll
    for (int r = 0; r < 16; ++r) {
      const float4 hv = *reinterpret_cast<const float4*>(&hs[r][k]);
      am[r] = fmaf(p0.x, hv.x, fmaf(p1.x, hv.y, fmaf(p2.x, hv.z, fmaf(p3.x, hv.w, am[r]))));
      av[r] = fmaf(p0.y, hv.x, fmaf(p1.y, hv.y, fmaf(p2.y, hv.z, fmaf(p3.y, hv.w, av[r]))));
    }
  }
  #pragma unroll
  for (int r = 0; r < 16; ++r) {
    int b = b0 + r;
    z[b * LATD + u] = am[r] + sqrtf(expf(av[r])) * z_noise[b * LATD + u];
  }
  if (u < HD_DEC) {
    #pragma unroll
    for (int r = 0; r < 16; ++r) {
      int b = b0 + r;
      h1w[b * HD_DEC + u] = 0.0f; c1w[b * HD_DEC + u] = 0.0f;
      h2w[b * HD_DEC + u] = 0.0f; c2w[b * HD_DEC + u] = 0.0f;
    }
  }
  if (u < 9) {
    #pragma unroll
    for (int r = 0; r < 16; ++r) {
      int b = b0 + r;
      int len = seq_len[b];
      dlq[b * 9 + u] = seq[(b * T_SZ + (len - 1)) * F_SZ + 21 + u];
    }
  }
}

// ---------------- decoder cell step: LSTM1 + LSTM2 + x=relu(h2@Wg1T+bg1) ----------------
__global__ __launch_bounds__(256) void dec_cell_kernel(
    const float* __restrict__ z, const float* __restrict__ dlq,
    const float* __restrict__ macro,
    float* __restrict__ h1w, float* __restrict__ c1w,
    float* __restrict__ h2w, float* __restrict__ c2w,
    const float4* __restrict__ P1I, const float4* __restrict__ P1H, const float* __restrict__ be1,
    const float4* __restrict__ P2I, const float4* __restrict__ P2H, const float* __restrict__ be2,
    const float* __restrict__ Wg1T, const float* __restrict__ bg1,
    float* __restrict__ xbuf, int t)
{
  const int tid = threadIdx.x;
  const int b0 = blockIdx.x * 16;
  __shared__ float di[16][DEC_IN_P];
  __shared__ float h1s[16][HD_DEC];
  __shared__ float h2s[16][HD_DEC];

  for (int i = tid; i < 16 * DEC_IN_P; i += 256) {
    int r = i / DEC_IN_P, k = i - r * DEC_IN_P;
    int b = b0 + r;
    float v;
    if (k < LATD)            v = z[b * LATD + k];
    else if (k < LATD + 9)   v = dlq[b * 9 + (k - LATD)];
    else if (k < DEC_IN)     v = macro[(b * 12 + t) * 14 + (k - LATD - 9)];
    else                     v = 0.0f;
    di[r][k] = v;
  }
  for (int i = tid; i < 16 * HD_DEC; i += 256) {
    int r = i / HD_DEC, k = i - r * HD_DEC;
    h1s[r][k] = h1w[(b0 + r) * HD_DEC + k];
    h2s[r][k] = h2w[(b0 + r) * HD_DEC + k];
  }

  const int u = tid & 127;
  const int grp = tid >> 7;       // 0/1 -> rows [0..8) / [8..16)
  const int r0 = grp * 8;
  const bool act = u < HD_DEC;

  float c1r[8], c2r[8];
  if (act) {
    #pragma unroll
    for (int r = 0; r < 8; ++r) {
      c1r[r] = c1w[(b0 + r0 + r) * HD_DEC + u];
      c2r[r] = c2w[(b0 + r0 + r) * HD_DEC + u];
    }
  }
  __syncthreads();

  // ---- LSTM1 gates ----
  float a0[8], a1[8], a2[8], a3[8];
  if (act) {
    const float b0g = be1[u], b1g = be1[100 + u], b2g = be1[200 + u], b3g = be1[300 + u];
    #pragma unroll
    for (int r = 0; r < 8; ++r) { a0[r] = b0g; a1[r] = b1g; a2[r] = b2g; a3[r] = b3g; }
    for (int k = 0; k < DEC_IN_P; k += 4) {
      const float4 w0 = P1I[(k + 0) * 100 + u];
      const float4 w1 = P1I[(k + 1) * 100 + u];
      const float4 w2 = P1I[(k + 2) * 100 + u];
      const float4 w3 = P1I[(k + 3) * 100 + u];
      #pragma unroll
      for (int r = 0; r < 8; ++r) {
        const float4 xv = *reinterpret_cast<const float4*>(&di[r0 + r][k]);
        GDOT(a0[r], x, w0, w1, w2, w3, xv);
        GDOT(a1[r], y, w0, w1, w2, w3, xv);
        GDOT(a2[r], z, w0, w1, w2, w3, xv);
        GDOT(a3[r], w, w0, w1, w2, w3, xv);
      }
    }
    for (int k = 0; k < HD_DEC; k += 4) {
      const float4 w0 = P1H[(k + 0) * 100 + u];
      const float4 w1 = P1H[(k + 1) * 100 + u];
      const float4 w2 = P1H[(k + 2) * 100 + u];
      const float4 w3 = P1H[(k + 3) * 100 + u];
      #pragma unroll
      for (int r = 0; r < 8; ++r) {
        const float4 hv = *reinterpret_cast<const float4*>(&h1s[r0 + r][k]);
        GDOT(a0[r], x, w0, w1, w2, w3, hv);
        GDOT(a1[r], y, w0, w1, w2, w3, hv);
        GDOT(a2[r], z, w0, w1, w2, w3, hv);
        GDOT(a3[r], w, w0, w1, w2, w3, hv);
      }
    }
  }
  __syncthreads();                 // h1s reads complete
  if (act) {
    #pragma unroll
    for (int r = 0; r < 8; ++r) {
      float ig = sigf(a0[r]), fg = sigf(a1[r]), gg = tanhf(a2[r]), og = sigf(a3[r]);
      float cn = fg * c1r[r] + ig * gg;
      float hn = og * tanhf(cn);
      int b = b0 + r0 + r;
      h1s[r0 + r][u] = hn;
      h1w[b * HD_DEC + u] = hn;
      c1w[b * HD_DEC + u] = cn;
    }
  }
  __syncthreads();                 // new h1 visible

  // ---- LSTM2 gates (x = new h1, h = old h2) ----
  if (act) {
    const float b0g = be2[u], b1g = be2[100 + u], b2g = be2[200 + u], b3g = be2[300 + u];
    #pragma unroll
    for (int r = 0; r < 8; ++r) { a0[r] = b0g; a1[r] = b1g; a2[r] = b2g; a3[r] = b3g; }
    for (int k = 0; k < HD_DEC; k += 4) {
      const float4 w0 = P2I[(k + 0) * 100 + u];
      const float4 w1 = P2I[(k + 1) * 100 + u];
      const float4 w2 = P2I[(k + 2) * 100 + u];
      const float4 w3 = P2I[(k + 3) * 100 + u];
      #pragma unroll
      for (int r = 0; r < 8; ++r) {
        const float4 hv = *reinterpret_cast<const float4*>(&h1s[r0 + r][k]);
        GDOT(a0[r], x, w0, w1, w2, w3, hv);
        GDOT(a1[r], y, w0, w1, w2, w3, hv);
        GDOT(a2[r], z, w0, w1, w2, w3, hv);
        GDOT(a3[r], w, w0, w1, w2, w3, hv);
      }
    }
    for (int k = 0; k < HD_DEC; k += 4) {
      const float4 w0 = P2H[(k + 0) * 100 + u];
      const float4 w1 = P2H[(k + 1) * 100 + u];
      const float4 w2 = P2H[(k + 2) * 100 + u];
      const float4 w3 = P2H[(k + 3) * 100 + u];
      #pragma unroll
      for (int r = 0; r < 8; ++r) {
        const float4 hv = *reinterpret_cast<const float4*>(&h2s[r0 + r][k]);
        GDOT(a0[r], x, w0, w1, w2, w3, hv);
        GDOT(a1[r], y, w0, w1, w2, w3, hv);
        GDOT(a2[r], z, w0, w1, w2, w3, hv);
        GDOT(a3[r], w, w0, w1, w2, w3, hv);
      }
    }
  }
  __syncthreads();                 // h2s reads complete
  if (act) {
    #pragma unroll
    for (int r = 0; r < 8; ++r) {
      float ig = sigf(a0[r]), fg = sigf(a1[r]), gg = tanhf(a2[r]), og = sigf(a3[r]);
      float cn = fg * c2r[r] + ig * gg;
      float hn = og * tanhf(cn);
      int b = b0 + r0 + r;
      h2s[r0 + r][u] = hn;
      h2w[b * HD_DEC + u] = hn;
      c2w[b * HD_DEC + u] = cn;
    }
  }
  __syncthreads();                 // new h2 visible

  // ---- x = relu(h2 @ Wg1T + bg1) ----
  for (int p = tid; p < 16 * 25; p += 256) {
    int r = p / 25, cc = p - r * 25;
    float s = bg1[cc];
    for (int k = 0; k < HD_DEC; k += 4) {
      const float4 hv = *reinterpret_cast<const float4*>(&h2s[r][k]);
      s += hv.x * Wg1T[k * 25 + cc] + hv.y * Wg1T[(k + 1) * 25 + cc]
         + hv.z * Wg1T[(k + 2) * 25 + cc] + hv.w * Wg1T[(k + 3) * 25 + cc];
    }
    xbuf[(b0 + r) * 25 + cc] = fmaxf(s, 0.0f);
  }
}

// ---------------- decoder batchnorm stats (deterministic tree reduce) ----------------
__global__ __launch_bounds__(256) void dec_stats_kernel(
    const float* __restrict__ xbuf, float* __restrict__ muv, float* __restrict__ rstdv)
{
  const int col = blockIdx.x;
  const int tid = threadIdx.x;
  __shared__ float red[256];
  float v[16];
  float s = 0.0f;
  #pragma unroll
  for (int i = 0; i < 16; ++i) { v[i] = xbuf[(tid + 256 * i) * 25 + col]; s += v[i]; }
  red[tid] = s; __syncthreads();
  for (int off = 128; off >= 1; off >>= 1) {
    if (tid < off) red[tid] += red[tid + off];
    __syncthreads();
  }
  float mean = red[0] / (float)B_SZ;
  __syncthreads();
  float s2 = 0.0f;
  #pragma unroll
  for (int i = 0; i < 16; ++i) { float d = v[i] - mean; s2 += d * d; }
  red[tid] = s2; __syncthreads();
  for (int off = 128; off >= 1; off >>= 1) {
    if (tid < off) red[tid] += red[tid + off];
    __syncthreads();
  }
  if (tid == 0) {
    muv[col] = mean;
    rstdv[col] = rsqrtf(red[0] / (float)B_SZ + 1e-5f);
  }
}

// ---------------- decoder normalize + dlq = xn@Wg2T + bg2, write output ----------------
__global__ __launch_bounds__(256) void dec_out_kernel(
    const float* __restrict__ xbuf, const float* __restrict__ muv, const float* __restrict__ rstdv,
    const float* __restrict__ gamma, const float* __restrict__ beta,
    const float* __restrict__ Wg2, const float* __restrict__ bg2,
    float* __restrict__ dlq, float* __restrict__ out, int t)
{
  int b = blockIdx.x * 256 + threadIdx.x;
  float xn[25];
  #pragma unroll
  for (int c = 0; c < 25; ++c)
    xn[c] = gamma[c] * (xbuf[b * 25 + c] - muv[c]) * rstdv[c] + beta[c];
  #pragma unroll
  for (int j = 0; j < 9; ++j) {
    float s = bg2[j];
    #pragma unroll
    for (int c = 0; c < 25; ++c) s += xn[c] * Wg2[j * 25 + c];
    dlq[b * 9 + j] = s;
    out[b * 108 + j * 12 + t] = s;
  }
}

// ---------------- host launch ----------------
extern "C" void kernel_launch(void* const* d_in, const int* in_sizes, int n_in,
                              void* d_out, int out_size, void* d_ws, size_t ws_size,
                              hipStream_t stream)
{
  const float* seq     = (const float*)d_in[0];
  const int*   seq_len = (const int*)  d_in[1];
  const int*   ymd     = (const int*)  d_in[2];
  const int*   acq     = (const int*)  d_in[3];
  const float* macro   = (const float*)d_in[4];
  const float* z_noise = (const float*)d_in[5];
  const float* Ea0 = (const float*)d_in[6];
  const float* Ea1 = (const float*)d_in[7];
  const float* Ea2 = (const float*)d_in[8];
  const float* Es0 = (const float*)d_in[9];
  const float* Es1 = (const float*)d_in[10];
  const float* Es2 = (const float*)d_in[11];
  const float* Wih_f = (const float*)d_in[12];
  const float* Whh_f = (const float*)d_in[13];
  const float* bih_f = (const float*)d_in[14];
  const float* bhh_f = (const float*)d_in[15];
  const float* Wih_b = (const float*)d_in[16];
  const float* Whh_b = (const float*)d_in[17];
  const float* bih_b = (const float*)d_in[18];
  const float* bhh_b = (const float*)d_in[19];
  const float* W_lat = (const float*)d_in[20];
  const float* b_lat = (const float*)d_in[21];
  const float* Wih1  = (const float*)d_in[22];
  const float* Whh1  = (const float*)d_in[23];
  const float* bih1  = (const float*)d_in[24];
  const float* bhh1  = (const float*)d_in[25];
  const float* Wih2  = (const float*)d_in[26];
  const float* Whh2  = (const float*)d_in[27];
  const float* bih2  = (const float*)d_in[28];
  const float* bhh2  = (const float*)d_in[29];
  const float* Wg1   = (const float*)d_in[30];
  const float* bg1   = (const float*)d_in[31];
  const float* gamma = (const float*)d_in[32];
  const float* beta  = (const float*)d_in[33];
  const float* Wg2   = (const float*)d_in[34];
  const float* bg2   = (const float*)d_in[35];

  float* ws  = (float*)d_ws;
  float* out = (float*)d_out;

  float* pihF = ws + OFF_PIH_F;
  float* phhF = ws + OFF_PHH_F;
  float* pihB = ws + OFF_PIH_B;
  float* phhB = ws + OFF_PHH_B;
  float* plat = ws + OFF_PLAT;
  float* p1i  = ws + OFF_P1I;
  float* p1h  = ws + OFF_P1H;
  float* p2i  = ws + OFF_P2I;
  float* p2h  = ws + OFF_P2H;
  float* wg1T = ws + OFF_WG1T;
  float* be_f = ws + OFF_BE_F;
  float* be_b = ws + OFF_BE_B;
  float* be1  = ws + OFF_BE1;
  float* be2  = ws + OFF_BE2;
  float* hf   = ws + OFF_HF;
  float* hb   = ws + OFF_HB;
  float* z    = ws + OFF_Z;
  float* h1w  = ws + OFF_H1;
  float* c1w  = ws + OFF_C1;
  float* h2w  = ws + OFF_H2;
  float* c2w  = ws + OFF_C2;
  float* dlq  = ws + OFF_DLQ;
  float* xbuf = ws + OFF_XBUF;
  float* muv  = ws + OFF_MU;
  float* rstdv= ws + OFF_RSTD;

  PrepArgs pa;
  int ji = 0;
  auto PK = [&](const float* s, float* d, int U, int C, int Kp, int G) {
    pa.j[ji].src = s; pa.j[ji].src2 = nullptr; pa.j[ji].dst = d;
    pa.j[ji].U = U; pa.j[ji].C = C; pa.j[ji].Kp = Kp; pa.j[ji].G = G; ++ji;
  };
  auto BS = [&](const float* a, const float* b, float* d, int n) {
    pa.j[ji].src = a; pa.j[ji].src2 = b; pa.j[ji].dst = d;
    pa.j[ji].U = n; pa.j[ji].C = 0; pa.j[ji].Kp = 0; pa.j[ji].G = 0; ++ji;
  };
  PK(Wih_f, pihF, 256, 74, 76, 4);
  PK(Whh_f, phhF, 256, 256, 256, 4);
  PK(Wih_b, pihB, 256, 74, 76, 4);
  PK(Whh_b, phhB, 256, 256, 256, 4);
  PK(W_lat, plat, 256, 256, 256, 2);
  PK(Wih1,  p1i,  100, 279, 280, 4);
  PK(Whh1,  p1h,  100, 100, 100, 4);
  PK(Wih2,  p2i,  100, 100, 100, 4);
  PK(Whh2,  p2h,  100, 100, 100, 4);
  PK(Wg1,   wg1T, 25, 100, 100, 1);
  BS(bih_f, bhh_f, be_f, 1024);
  BS(bih_b, bhh_b, be_b, 1024);
  BS(bih1,  bhh1,  be1,  400);
  BS(bih2,  bhh2,  be2,  400);

  prep_kernel<<<512, 256, 0, stream>>>(pa);

  enc_kernel<<<256, 1024, 0, stream>>>(
      seq, seq_len, ymd, acq, Ea0, Ea1, Ea2, Es0, Es1, Es2,
      (const float4*)pihF, (const float4*)phhF, be_f,
      (const float4*)pihB, (const float4*)phhB, be_b, hf, hb);

  latent_kernel<<<256, 256, 0, stream>>>(
      hf, hb, (const float2*)plat, b_lat, z_noise, seq, seq_len,
      z, dlq, h1w, c1w, h2w, c2w);

  for (int t = 0; t < 12; ++t) {
    dec_cell_kernel<<<256, 256, 0, stream>>>(
        z, dlq, macro, h1w, c1w, h2w, c2w,
        (const float4*)p1i, (const float4*)p1h, be1,
        (const float4*)p2i, (const float4*)p2h, be2, wg1T, bg1, xbuf, t);
    dec_stats_kernel<<<25, 256, 0, stream>>>(xbuf, muv, rstdv);
    dec_out_kernel<<<16, 256, 0, stream>>>(
        xbuf, muv, rstdv, gamma, beta, Wg2, bg2, dlq, out, t);
  }
}